// Round 9
// baseline (91.288 us; speedup 1.0000x reference)
//
#include <hip/hip_runtime.h>
#include <math.h>

#define BB 32
#define CC 128
#define HW 1024
#define NG 32
#define TPG 4096
#define QSZ ((size_t)BB * 4 * HW * 32)   // elems per Q/K/V bf16 buffer

typedef __attribute__((ext_vector_type(8))) short fragAB;
typedef __attribute__((ext_vector_type(4))) float fragC;

__device__ __forceinline__ ushort f2bf(float f) {
  union { float f; uint u; } v; v.f = f;
  uint r = v.u + 0x7FFFu + ((v.u >> 16) & 1u);
  return (ushort)(r >> 16);
}
// pack two f32 -> two bf16 (truncation) in one v_perm_b32
__device__ __forceinline__ uint pack2(float lo, float hi) {
  return __builtin_amdgcn_perm(__float_as_uint(hi), __float_as_uint(lo), 0x07060302u);
}

// LDS swizzle (byte offsets), 128B rows, g = 16B granule 0..7
__device__ __forceinline__ int vswz(int row, int g) {
  return row * 128 + 16 * (g ^ (row & 7));
}

// ---------------- GroupNorm stats (blocks 0..1023) + weight bf16 prep (1024..1279) ----
__global__ __launch_bounds__(256) void gn_stats(const float* __restrict__ x,
    float2* __restrict__ stats, const float* __restrict__ qkvw,
    const float* __restrict__ projw, ushort* __restrict__ wq16,
    ushort* __restrict__ wp16) {
  if (blockIdx.x >= 1024) {
    int idx = (blockIdx.x - 1024) * 256 + threadIdx.x;   // 0..65535
    if (idx < 49152) wq16[idx] = f2bf(qkvw[idx]);
    else             wp16[idx - 49152] = f2bf(projw[idx - 49152]);
    return;
  }
  int blk = blockIdx.x;          // b*NG + g
  int b = blk >> 5, g = blk & 31;
  const float4* xp4 = (const float4*)(x + ((size_t)(b * CC + g * 4)) * HW);
  float s = 0.f, s2 = 0.f;
  #pragma unroll
  for (int i = 0; i < 4; ++i) {
    float4 v = xp4[threadIdx.x + i * 256];
    s  += v.x + v.y + v.z + v.w;
    s2 += v.x * v.x + v.y * v.y + v.z * v.z + v.w * v.w;
  }
  #pragma unroll
  for (int off = 32; off; off >>= 1) {
    s  += __shfl_down(s, off, 64);
    s2 += __shfl_down(s2, off, 64);
  }
  __shared__ float ls[4], ls2[4];
  int lane = threadIdx.x & 63, wid = threadIdx.x >> 6;
  if (lane == 0) { ls[wid] = s; ls2[wid] = s2; }
  __syncthreads();
  if (threadIdx.x == 0) {
    float a  = ls[0] + ls[1] + ls[2] + ls[3];
    float a2 = ls2[0] + ls2[1] + ls2[2] + ls2[3];
    float mu = a * (1.f / TPG);
    float var = a2 * (1.f / TPG) - mu * mu;
    stats[blk] = make_float2(mu, rsqrtf(var + 1e-5f));
  }
}

// ---------------- GN apply + transpose: x[b][c][t] -> xt16[b][t][c] bf16 ----------------
__global__ __launch_bounds__(256) void gn_apply(const float* __restrict__ x,
    const float2* __restrict__ stats, const float* __restrict__ gw,
    const float* __restrict__ gb, ushort* __restrict__ xt16) {
  __shared__ ushort Xs[64][136];
  int b = blockIdx.x >> 4, t0 = (blockIdx.x & 15) * 64;
  int tid = threadIdx.x;
  int tq = tid & 15, cg = (tid >> 4) & 3, wv = tid >> 6;

  #pragma unroll
  for (int iter = 0; iter < 8; ++iter) {
    int c = wv * 4 + cg + iter * 16;
    float2 st = stats[b * 32 + (c >> 2)];
    float wsc = gw[c] * st.y;
    float bsc = gb[c] - st.x * wsc;
    const float* xp = x + ((size_t)b * CC + c) * HW + t0;
    #pragma unroll
    for (int j = 0; j < 4; ++j) {
      int t = tq + 16 * j;
      Xs[t][c] = f2bf(xp[t] * wsc + bsc);
    }
  }
  __syncthreads();
  #pragma unroll
  for (int it = 0; it < 4; ++it) {
    int row = (tid >> 4) + it * 16;
    int c8 = tid & 15;
    uint4 v = *(uint4*)&Xs[row][c8 * 8];
    *(uint4*)&xt16[((size_t)b * HW + t0 + row) * CC + c8 * 8] = v;
  }
}

// ---------------- MFMA GEMM: D[o,t] = sum_c W[o,c] * X[t,c] ----------------
template<int PROJ>
__global__ __launch_bounds__(256) void mgemm(
    const ushort* __restrict__ W16, const ushort* __restrict__ X16,
    ushort* __restrict__ Qb, float* __restrict__ out,
    const float* __restrict__ bias, const float* __restrict__ resid) {
  __shared__ ushort Xs[64 * 128];    // 16KB, XOR-swizzled byte ^= ((row&7)<<4)
  int b = blockIdx.z, o0 = blockIdx.y * 64, t0 = blockIdx.x * 64;
  int tid = threadIdx.x;
  int lane = tid & 63, w = tid >> 6, lc = lane & 15, lg = lane >> 4;
  int wo = w >> 1, wt = w & 1;

  fragAB af[2][4];
  #pragma unroll
  for (int i = 0; i < 2; ++i)
    #pragma unroll
    for (int kc = 0; kc < 4; ++kc)
      af[i][kc] = *(const fragAB*)&W16[(size_t)(o0 + wo * 32 + i * 16 + lc) * 128 + kc * 32 + lg * 8];

  {
    const char* src = (const char*)(X16 + ((size_t)b * HW + t0) * CC);
    char* dst = (char*)Xs;
    #pragma unroll
    for (int it = 0; it < 4; ++it) {
      int flat = tid * 16 + it * 4096;
      uint4 v = *(const uint4*)(src + flat);
      *(uint4*)(dst + (flat ^ (((flat >> 8) & 7) << 4))) = v;
    }
  }
  __syncthreads();

  fragC acc[2][2];
  #pragma unroll
  for (int i = 0; i < 2; ++i)
    #pragma unroll
    for (int j = 0; j < 2; ++j)
      acc[i][j] = (fragC){0.f, 0.f, 0.f, 0.f};

  #pragma unroll
  for (int kc = 0; kc < 4; ++kc) {
    fragAB bf[2];
    #pragma unroll
    for (int j = 0; j < 2; ++j) {
      int row = wt * 32 + j * 16 + lc;
      int byt = (row * 256 + kc * 64 + lg * 16) ^ ((row & 7) << 4);
      bf[j] = *(const fragAB*)((const char*)Xs + byt);
    }
    #pragma unroll
    for (int i = 0; i < 2; ++i)
      #pragma unroll
      for (int j = 0; j < 2; ++j)
        acc[i][j] = __builtin_amdgcn_mfma_f32_16x16x32_bf16(af[i][kc], bf[j], acc[i][j], 0, 0, 0);
  }

  if constexpr (PROJ == 0) {
    #pragma unroll
    for (int i = 0; i < 2; ++i) {
      int ob = o0 + wo * 32 + i * 16;
      int blk = ob >> 5;
      int hh = blk / 3, kind = blk % 3;  // 0=q,1=k,2=v
      int cb = ob & 16;
      size_t bh = (size_t)b * 4 + hh;
      // q rows: fold logits scale 1/dh AND log2(e) so attn uses exp2 directly
      float sc = (kind == 0) ? (0.03125f * 1.44269504f) : 1.f;
      #pragma unroll
      for (int j = 0; j < 2; ++j) {
        int t = t0 + wt * 32 + j * 16 + lc;
        if (kind < 2) {
          ushort* dst = (kind == 0) ? Qb : (Qb + QSZ);
          ushort4 rv;
          rv.x = f2bf(acc[i][j][0] * sc); rv.y = f2bf(acc[i][j][1] * sc);
          rv.z = f2bf(acc[i][j][2] * sc); rv.w = f2bf(acc[i][j][3] * sc);
          *(ushort4*)&dst[(bh * HW + t) * 32 + cb + lg * 4] = rv;
        } else {
          ushort* Vb = Qb + 2 * QSZ;
          #pragma unroll
          for (int r = 0; r < 4; ++r)
            Vb[(bh * 32 + cb + lg * 4 + r) * HW + t] = f2bf(acc[i][j][r]);
        }
      }
    }
  } else {
    #pragma unroll
    for (int i = 0; i < 2; ++i)
      #pragma unroll
      for (int j = 0; j < 2; ++j) {
        int t = t0 + wt * 32 + j * 16 + lc;
        #pragma unroll
        for (int r = 0; r < 4; ++r) {
          int o = o0 + wo * 32 + i * 16 + lg * 4 + r;
          size_t idx = ((size_t)b * CC + o) * HW + t;
          out[idx] = acc[i][j][r] + bias[o] + resid[idx];
        }
      }
  }
}

// ---------------- MFMA flash attention v6: 1 wave/block, zero barriers ----------------
// K/V frag loads DIRECT from global (L2-resident per XCD: 16 heads x 128KB = 2MB).
// Static softmax with exp2 (q prescaled by (1/32)*log2e). Ps wave-private in LDS.
__global__ __launch_bounds__(64) void attn3(
    const ushort* __restrict__ Qb, const ushort* __restrict__ Kb,
    const ushort* __restrict__ Vb, ushort* __restrict__ ao16) {
  __shared__ char arena[6144];   // Ps0 [0,2K), Ps1 [2K,4K), Ol overlaps [0,2.5K)

  int lin = blockIdx.x;
  int wl = (lin & 7) * 512 + (lin >> 3);   // XCD swizzle: 16 heads per XCD
  int tb = wl & 31;                        // 32 q-tiles of 32
  int bh = wl >> 5;
  int h = bh & 3, b = bh >> 2;

  int lane = threadIdx.x;
  int lc = lane & 15, lg = lane >> 4;

  const ushort* Qg = Qb + (size_t)bh * HW * 32;
  const ushort* Kg = Kb + (size_t)bh * HW * 32;
  const ushort* Vg = Vb + (size_t)bh * HW * 32;
  int t0 = tb * 32;

  fragAB q0 = *(const fragAB*)&Qg[(size_t)(t0 + lc) * 32 + lg * 8];
  fragAB q1 = *(const fragAB*)&Qg[(size_t)(t0 + 16 + lc) * 32 + lg * 8];

  fragC a00 = {0.f,0.f,0.f,0.f}, a01 = {0.f,0.f,0.f,0.f};
  fragC a10 = {0.f,0.f,0.f,0.f}, a11 = {0.f,0.f,0.f,0.f};
  float l0 = 0.f, l1 = 0.f;

  char* PsB0 = arena;
  char* PsB1 = arena + 2048;

  for (int i = 0; i < 16; ++i) {
    int s0 = i * 64;
    // K frags direct from global: rows s0+j*16+lc, 16B each -> 1KB contiguous/instr
    fragAB kf[4];
    #pragma unroll
    for (int j = 0; j < 4; ++j)
      kf[j] = *(const fragAB*)&Kg[(size_t)(s0 + j * 16 + lc) * 32 + lg * 8];
    // V frags direct from global: 16 rows x 64B sectors
    fragAB vf[2][2];
    #pragma unroll
    for (int cs = 0; cs < 2; ++cs)
      #pragma unroll
      for (int ks = 0; ks < 2; ++ks)
        vf[cs][ks] = *(const fragAB*)&Vg[(size_t)(cs * 16 + lc) * HW + s0 + ks * 32 + lg * 8];

    #pragma unroll
    for (int ts = 0; ts < 2; ++ts) {
      fragAB qf = ts ? q1 : q0;
      char* PsB = ts ? PsB1 : PsB0;
      fragC S[4];
      #pragma unroll
      for (int j = 0; j < 4; ++j) {
        fragC z = {0.f,0.f,0.f,0.f};
        S[j] = __builtin_amdgcn_mfma_f32_16x16x32_bf16(kf[j], qf, z, 0, 0, 0);
      }
      float rs = 0.f;
      #pragma unroll
      for (int j = 0; j < 4; ++j) {
        float p0 = exp2f(S[j][0]), p1 = exp2f(S[j][1]);
        float p2 = exp2f(S[j][2]), p3 = exp2f(S[j][3]);
        rs += (p0 + p1) + (p2 + p3);
        uint2 wv2;
        wv2.x = pack2(p0, p1);
        wv2.y = pack2(p2, p3);
        int g = j * 2 + (lg >> 1);
        *(uint2*)(PsB + lc * 128 + 16 * (g ^ (lc & 7)) + (lg & 1) * 8) = wv2;
      }
      if (ts) l1 += rs; else l0 += rs;
      fragC* aA = ts ? &a01 : &a00;
      fragC* aB = ts ? &a11 : &a10;
      fragAB bp0 = *(const fragAB*)(PsB + vswz(lc, lg));
      fragAB bp1 = *(const fragAB*)(PsB + vswz(lc, 4 + lg));
      *aA = __builtin_amdgcn_mfma_f32_16x16x32_bf16(vf[0][0], bp0, *aA, 0, 0, 0);
      *aA = __builtin_amdgcn_mfma_f32_16x16x32_bf16(vf[0][1], bp1, *aA, 0, 0, 0);
      *aB = __builtin_amdgcn_mfma_f32_16x16x32_bf16(vf[1][0], bp0, *aB, 0, 0, 0);
      *aB = __builtin_amdgcn_mfma_f32_16x16x32_bf16(vf[1][1], bp1, *aB, 0, 0, 0);
    }
  }

  // single cross-lane l reduce
  l0 += __shfl_xor(l0, 16); l0 += __shfl_xor(l0, 32);
  l1 += __shfl_xor(l1, 16); l1 += __shfl_xor(l1, 32);
  float il0 = 1.f / l0, il1 = 1.f / l1;

  // O -> Ol[t][c] (80B rows) -> coalesced global; same-wave LDS, no barrier needed
  ushort* Ol = (ushort*)arena;
  uint2 u;
  u.x = pack2(a00[0] * il0, a00[1] * il0); u.y = pack2(a00[2] * il0, a00[3] * il0);
  *(uint2*)&Ol[lc * 40 + lg * 4] = u;
  u.x = pack2(a10[0] * il0, a10[1] * il0); u.y = pack2(a10[2] * il0, a10[3] * il0);
  *(uint2*)&Ol[lc * 40 + 16 + lg * 4] = u;
  u.x = pack2(a01[0] * il1, a01[1] * il1); u.y = pack2(a01[2] * il1, a01[3] * il1);
  *(uint2*)&Ol[(lc + 16) * 40 + lg * 4] = u;
  u.x = pack2(a11[0] * il1, a11[1] * il1); u.y = pack2(a11[2] * il1, a11[3] * il1);
  *(uint2*)&Ol[(lc + 16) * 40 + 16 + lg * 4] = u;

  int row = lane >> 1, half = lane & 1;
  uint4 v0 = *(uint4*)&Ol[row * 40 + half * 16];
  uint4 v1 = *(uint4*)&Ol[row * 40 + half * 16 + 8];
  ushort* dst = &ao16[((size_t)b * HW + t0 + row) * CC + h * 32 + half * 16];
  *(uint4*)dst = v0;
  *(uint4*)(dst + 8) = v1;
}

extern "C" void kernel_launch(void* const* d_in, const int* in_sizes, int n_in,
                              void* d_out, int out_size, void* d_ws, size_t ws_size,
                              hipStream_t stream) {
  (void)in_sizes; (void)n_in; (void)out_size; (void)ws_size;
  const float* x     = (const float*)d_in[0];
  const float* gw    = (const float*)d_in[1];
  const float* gb    = (const float*)d_in[2];
  const float* qkvw  = (const float*)d_in[3];
  const float* projw = (const float*)d_in[4];
  const float* projb = (const float*)d_in[5];
  float* out = (float*)d_out;

  char* wsb = (char*)d_ws;
  ushort* xt16 = (ushort*)wsb;                              // 8 MB (GN out, then attn out)
  ushort* Qb   = (ushort*)(wsb + ((size_t)8 << 20));        // 8 MB
  ushort* Kb   = Qb + QSZ;                                  // 8 MB
  ushort* Vb   = Qb + 2 * QSZ;                              // 8 MB
  ushort* wq16 = (ushort*)(wsb + ((size_t)32 << 20));       // 96 KB
  ushort* wp16 = (ushort*)(wsb + ((size_t)32 << 20) + (128 << 10)); // 32 KB
  float2* stats = (float2*)(wsb + ((size_t)32 << 20) + (256 << 10)); // 8 KB

  gn_stats<<<dim3(BB * NG + 256), 256, 0, stream>>>(x, stats, qkvw, projw, wq16, wp16);
  gn_apply<<<dim3(BB * 16), 256, 0, stream>>>(x, stats, gw, gb, xt16);
  mgemm<0><<<dim3(16, 6, BB), 256, 0, stream>>>(wq16, xt16, Qb, nullptr, nullptr, nullptr);
  attn3<<<dim3(4096), 64, 0, stream>>>(Qb, Kb, Vb, xt16);
  mgemm<1><<<dim3(16, 2, BB), 256, 0, stream>>>(wp16, xt16, nullptr, out, projb, x);
}

// Round 10
// 83.654 us; speedup vs baseline: 1.0913x; 1.0913x over previous
//
#include <hip/hip_runtime.h>
#include <math.h>

#define BB 32
#define CC 128
#define HW 1024
#define NG 32
#define TPG 4096
#define QSZ ((size_t)BB * 4 * HW * 32)   // elems per Q/K/V bf16 buffer

typedef __attribute__((ext_vector_type(8))) short fragAB;
typedef __attribute__((ext_vector_type(4))) float fragC;

__device__ __forceinline__ ushort f2bf(float f) {
  union { float f; uint u; } v; v.f = f;
  uint r = v.u + 0x7FFFu + ((v.u >> 16) & 1u);
  return (ushort)(r >> 16);
}
// pack two f32 -> two bf16 (truncation) in one v_perm_b32
__device__ __forceinline__ uint pack2(float lo, float hi) {
  return __builtin_amdgcn_perm(__float_as_uint(hi), __float_as_uint(lo), 0x07060302u);
}

// LDS swizzles (byte offsets).
__device__ __forceinline__ int kswz(int row, int g) {   // 64B rows, g=16B granule 0..3
  return row * 64 + 16 * (g ^ ((row >> 1) & 3));
}
__device__ __forceinline__ int vswz(int row, int g) {   // 128B rows, g 0..7
  return row * 128 + 16 * (g ^ (row & 7));
}

// ---------------- GroupNorm stats (blocks 0..1023) + weight bf16 prep (1024..1279) ----
__global__ __launch_bounds__(256) void gn_stats(const float* __restrict__ x,
    float2* __restrict__ stats, const float* __restrict__ qkvw,
    const float* __restrict__ projw, ushort* __restrict__ wq16,
    ushort* __restrict__ wp16) {
  if (blockIdx.x >= 1024) {
    int idx = (blockIdx.x - 1024) * 256 + threadIdx.x;   // 0..65535
    if (idx < 49152) wq16[idx] = f2bf(qkvw[idx]);
    else             wp16[idx - 49152] = f2bf(projw[idx - 49152]);
    return;
  }
  int blk = blockIdx.x;          // b*NG + g
  int b = blk >> 5, g = blk & 31;
  const float4* xp4 = (const float4*)(x + ((size_t)(b * CC + g * 4)) * HW);
  float s = 0.f, s2 = 0.f;
  #pragma unroll
  for (int i = 0; i < 4; ++i) {
    float4 v = xp4[threadIdx.x + i * 256];
    s  += v.x + v.y + v.z + v.w;
    s2 += v.x * v.x + v.y * v.y + v.z * v.z + v.w * v.w;
  }
  #pragma unroll
  for (int off = 32; off; off >>= 1) {
    s  += __shfl_down(s, off, 64);
    s2 += __shfl_down(s2, off, 64);
  }
  __shared__ float ls[4], ls2[4];
  int lane = threadIdx.x & 63, wid = threadIdx.x >> 6;
  if (lane == 0) { ls[wid] = s; ls2[wid] = s2; }
  __syncthreads();
  if (threadIdx.x == 0) {
    float a  = ls[0] + ls[1] + ls[2] + ls[3];
    float a2 = ls2[0] + ls2[1] + ls2[2] + ls2[3];
    float mu = a * (1.f / TPG);
    float var = a2 * (1.f / TPG) - mu * mu;
    stats[blk] = make_float2(mu, rsqrtf(var + 1e-5f));
  }
}

// ---------------- GN apply + transpose: x[b][c][t] -> xt16[b][t][c] bf16 ----------------
__global__ __launch_bounds__(256) void gn_apply(const float* __restrict__ x,
    const float2* __restrict__ stats, const float* __restrict__ gw,
    const float* __restrict__ gb, ushort* __restrict__ xt16) {
  __shared__ ushort Xs[64][136];
  int b = blockIdx.x >> 4, t0 = (blockIdx.x & 15) * 64;
  int tid = threadIdx.x;
  int tq = tid & 15, cg = (tid >> 4) & 3, wv = tid >> 6;

  #pragma unroll
  for (int iter = 0; iter < 8; ++iter) {
    int c = wv * 4 + cg + iter * 16;
    float2 st = stats[b * 32 + (c >> 2)];
    float wsc = gw[c] * st.y;
    float bsc = gb[c] - st.x * wsc;
    const float* xp = x + ((size_t)b * CC + c) * HW + t0;
    #pragma unroll
    for (int j = 0; j < 4; ++j) {
      int t = tq + 16 * j;
      Xs[t][c] = f2bf(xp[t] * wsc + bsc);
    }
  }
  __syncthreads();
  #pragma unroll
  for (int it = 0; it < 4; ++it) {
    int row = (tid >> 4) + it * 16;
    int c8 = tid & 15;
    uint4 v = *(uint4*)&Xs[row][c8 * 8];
    *(uint4*)&xt16[((size_t)b * HW + t0 + row) * CC + c8 * 8] = v;
  }
}

// ---------------- MFMA GEMM: D[o,t] = sum_c W[o,c] * X[t,c] ----------------
template<int PROJ>
__global__ __launch_bounds__(256) void mgemm(
    const ushort* __restrict__ W16, const ushort* __restrict__ X16,
    ushort* __restrict__ Qb, float* __restrict__ out,
    const float* __restrict__ bias, const float* __restrict__ resid) {
  __shared__ ushort Xs[64 * 128];    // 16KB, XOR-swizzled byte ^= ((row&7)<<4)
  int b = blockIdx.z, o0 = blockIdx.y * 64, t0 = blockIdx.x * 64;
  int tid = threadIdx.x;
  int lane = tid & 63, w = tid >> 6, lc = lane & 15, lg = lane >> 4;
  int wo = w >> 1, wt = w & 1;

  fragAB af[2][4];
  #pragma unroll
  for (int i = 0; i < 2; ++i)
    #pragma unroll
    for (int kc = 0; kc < 4; ++kc)
      af[i][kc] = *(const fragAB*)&W16[(size_t)(o0 + wo * 32 + i * 16 + lc) * 128 + kc * 32 + lg * 8];

  {
    const char* src = (const char*)(X16 + ((size_t)b * HW + t0) * CC);
    char* dst = (char*)Xs;
    #pragma unroll
    for (int it = 0; it < 4; ++it) {
      int flat = tid * 16 + it * 4096;
      uint4 v = *(const uint4*)(src + flat);
      *(uint4*)(dst + (flat ^ (((flat >> 8) & 7) << 4))) = v;
    }
  }
  __syncthreads();

  fragC acc[2][2];
  #pragma unroll
  for (int i = 0; i < 2; ++i)
    #pragma unroll
    for (int j = 0; j < 2; ++j)
      acc[i][j] = (fragC){0.f, 0.f, 0.f, 0.f};

  #pragma unroll
  for (int kc = 0; kc < 4; ++kc) {
    fragAB bf[2];
    #pragma unroll
    for (int j = 0; j < 2; ++j) {
      int row = wt * 32 + j * 16 + lc;
      int byt = (row * 256 + kc * 64 + lg * 16) ^ ((row & 7) << 4);
      bf[j] = *(const fragAB*)((const char*)Xs + byt);
    }
    #pragma unroll
    for (int i = 0; i < 2; ++i)
      #pragma unroll
      for (int j = 0; j < 2; ++j)
        acc[i][j] = __builtin_amdgcn_mfma_f32_16x16x32_bf16(af[i][kc], bf[j], acc[i][j], 0, 0, 0);
  }

  if constexpr (PROJ == 0) {
    #pragma unroll
    for (int i = 0; i < 2; ++i) {
      int ob = o0 + wo * 32 + i * 16;
      int blk = ob >> 5;
      int hh = blk / 3, kind = blk % 3;  // 0=q,1=k,2=v
      int cb = ob & 16;
      size_t bh = (size_t)b * 4 + hh;
      // q rows: fold logits scale 1/dh AND log2(e) so attn uses exp2 directly
      float sc = (kind == 0) ? (0.03125f * 1.44269504f) : 1.f;
      #pragma unroll
      for (int j = 0; j < 2; ++j) {
        int t = t0 + wt * 32 + j * 16 + lc;
        if (kind < 2) {
          ushort* dst = (kind == 0) ? Qb : (Qb + QSZ);
          ushort4 rv;
          rv.x = f2bf(acc[i][j][0] * sc); rv.y = f2bf(acc[i][j][1] * sc);
          rv.z = f2bf(acc[i][j][2] * sc); rv.w = f2bf(acc[i][j][3] * sc);
          *(ushort4*)&dst[(bh * HW + t) * 32 + cb + lg * 4] = rv;
        } else {
          ushort* Vb = Qb + 2 * QSZ;
          #pragma unroll
          for (int r = 0; r < 4; ++r)
            Vb[(bh * 32 + cb + lg * 4 + r) * HW + t] = f2bf(acc[i][j][r]);
        }
      }
    }
  } else {
    #pragma unroll
    for (int i = 0; i < 2; ++i)
      #pragma unroll
      for (int j = 0; j < 2; ++j) {
        int t = t0 + wt * 32 + j * 16 + lc;
        #pragma unroll
        for (int r = 0; r < 4; ++r) {
          int o = o0 + wo * 32 + i * 16 + lg * 4 + r;
          size_t idx = ((size_t)b * CC + o) * HW + t;
          out[idx] = acc[i][j][r] + bias[o] + resid[idx];
        }
      }
  }
}

// ---------------- MFMA flash attention v7: v4 structure, 16 q/wave ----------------
// 4 waves/block, 64 q/block, grid 2048. K/V LDS dbuf (kswz/vswz), static softmax
// exp2 (q prescaled (1/32)*log2e), wave-private Ps, Ol transpose epilogue.
__global__ __launch_bounds__(256) void attn4(
    const ushort* __restrict__ Qb, const ushort* __restrict__ Kb,
    const ushort* __restrict__ Vb, ushort* __restrict__ ao16) {
  __shared__ char arena[24576];
  // [0,8K): Kl dbuf  [8K,16K): Vl dbuf  [16K,24K): Ps[w] 2KB each; Ol overlaps Ps

  int lin = blockIdx.x;
  int wl = (lin & 7) * 256 + (lin >> 3);   // XCD swizzle: 16 heads per XCD
  int tb = wl & 15;
  int bh = wl >> 4;
  int h = bh & 3, b = bh >> 2;

  int tid = threadIdx.x;
  int w = tid >> 6, lane = tid & 63, lc = lane & 15, lg = lane >> 4;

  const ushort* Qg = Qb + (size_t)bh * HW * 32;
  const ushort* Kg = Kb + (size_t)bh * HW * 32;
  const ushort* Vg = Vb + (size_t)bh * HW * 32;
  int t0 = tb * 64 + w * 16;

  fragAB q0 = *(const fragAB*)&Qg[(size_t)(t0 + lc) * 32 + lg * 8];

  fragC a0 = {0.f,0.f,0.f,0.f}, a1 = {0.f,0.f,0.f,0.f};
  float l0 = 0.f;

  int kdst = kswz(tid >> 2, tid & 3);
  int vrow = tid >> 3, vg = tid & 7;
  int vdst = vswz(vrow, vg);
  char* KlB0 = arena;           char* KlB1 = arena + 4096;
  char* VlB0 = arena + 8192;    char* VlB1 = arena + 12288;
  char* PsB  = arena + 16384 + w * 2048;

  uint4 kreg = *(const uint4*)&Kg[tid * 8];
  uint4 vreg = *(const uint4*)&Vg[(size_t)vrow * HW + vg * 8];
  *(uint4*)(KlB0 + kdst) = kreg;
  *(uint4*)(VlB0 + vdst) = vreg;
  __syncthreads();

  for (int i = 0; i < 16; ++i) {
    int cur = i & 1;
    char* KlC = cur ? KlB1 : KlB0;
    char* VlC = cur ? VlB1 : VlB0;
    if (i < 15) {
      int sn = (i + 1) * 64;
      kreg = *(const uint4*)&Kg[sn * 32 + tid * 8];
      vreg = *(const uint4*)&Vg[(size_t)vrow * HW + sn + vg * 8];
    }
    fragAB kf[4];
    #pragma unroll
    for (int j = 0; j < 4; ++j)
      kf[j] = *(const fragAB*)(KlC + kswz(j * 16 + lc, lg));
    fragAB vf[2][2];
    #pragma unroll
    for (int cs = 0; cs < 2; ++cs)
      #pragma unroll
      for (int ks = 0; ks < 2; ++ks)
        vf[cs][ks] = *(const fragAB*)(VlC + vswz(cs * 16 + lc, ks * 4 + lg));

    fragC S[4];
    #pragma unroll
    for (int j = 0; j < 4; ++j) {
      fragC z = {0.f,0.f,0.f,0.f};
      S[j] = __builtin_amdgcn_mfma_f32_16x16x32_bf16(kf[j], q0, z, 0, 0, 0);
    }
    float rs = 0.f;
    #pragma unroll
    for (int j = 0; j < 4; ++j) {
      float p0 = __builtin_amdgcn_exp2f(S[j][0]), p1 = __builtin_amdgcn_exp2f(S[j][1]);
      float p2 = __builtin_amdgcn_exp2f(S[j][2]), p3 = __builtin_amdgcn_exp2f(S[j][3]);
      rs += (p0 + p1) + (p2 + p3);
      uint2 wv2;
      wv2.x = pack2(p0, p1);
      wv2.y = pack2(p2, p3);
      int g = j * 2 + (lg >> 1);
      *(uint2*)(PsB + lc * 128 + 16 * (g ^ (lc & 7)) + (lg & 1) * 8) = wv2;
    }
    l0 += rs;
    fragAB bp0 = *(const fragAB*)(PsB + vswz(lc, lg));
    fragAB bp1 = *(const fragAB*)(PsB + vswz(lc, 4 + lg));
    a0 = __builtin_amdgcn_mfma_f32_16x16x32_bf16(vf[0][0], bp0, a0, 0, 0, 0);
    a0 = __builtin_amdgcn_mfma_f32_16x16x32_bf16(vf[0][1], bp1, a0, 0, 0, 0);
    a1 = __builtin_amdgcn_mfma_f32_16x16x32_bf16(vf[1][0], bp0, a1, 0, 0, 0);
    a1 = __builtin_amdgcn_mfma_f32_16x16x32_bf16(vf[1][1], bp1, a1, 0, 0, 0);

    if (i < 15) {
      char* KlN = cur ? KlB0 : KlB1;
      char* VlN = cur ? VlB0 : VlB1;
      *(uint4*)(KlN + kdst) = kreg;
      *(uint4*)(VlN + vdst) = vreg;
    }
    __syncthreads();
  }

  // single cross-lane l reduce (each lane summed a disjoint s-slice)
  l0 += __shfl_xor(l0, 16); l0 += __shfl_xor(l0, 32);
  float il0 = 1.f / l0;

  // O -> Ol[t][c] (80B rows, <=2-way) -> coalesced global
  ushort* Ol = (ushort*)(arena + 16384);   // overlaps Ps, after final barrier
  int tl = w * 16 + lc;
  uint2 u;
  u.x = pack2(a0[0] * il0, a0[1] * il0); u.y = pack2(a0[2] * il0, a0[3] * il0);
  *(uint2*)&Ol[tl * 40 + lg * 4] = u;
  u.x = pack2(a1[0] * il0, a1[1] * il0); u.y = pack2(a1[2] * il0, a1[3] * il0);
  *(uint2*)&Ol[tl * 40 + 16 + lg * 4] = u;
  __syncthreads();

  // 64 rows x 64B: 4 threads/row, uint4 each
  int row = tid >> 2, q4 = tid & 3;
  uint4 v = *(uint4*)&Ol[row * 40 + q4 * 8];
  *(uint4*)&ao16[((size_t)b * HW + tb * 64 + row) * CC + h * 32 + q4 * 8] = v;
}

extern "C" void kernel_launch(void* const* d_in, const int* in_sizes, int n_in,
                              void* d_out, int out_size, void* d_ws, size_t ws_size,
                              hipStream_t stream) {
  (void)in_sizes; (void)n_in; (void)out_size; (void)ws_size;
  const float* x     = (const float*)d_in[0];
  const float* gw    = (const float*)d_in[1];
  const float* gb    = (const float*)d_in[2];
  const float* qkvw  = (const float*)d_in[3];
  const float* projw = (const float*)d_in[4];
  const float* projb = (const float*)d_in[5];
  float* out = (float*)d_out;

  char* wsb = (char*)d_ws;
  ushort* xt16 = (ushort*)wsb;                              // 8 MB (GN out, then attn out)
  ushort* Qb   = (ushort*)(wsb + ((size_t)8 << 20));        // 8 MB
  ushort* Kb   = Qb + QSZ;                                  // 8 MB
  ushort* Vb   = Qb + 2 * QSZ;                              // 8 MB
  ushort* wq16 = (ushort*)(wsb + ((size_t)32 << 20));       // 96 KB
  ushort* wp16 = (ushort*)(wsb + ((size_t)32 << 20) + (128 << 10)); // 32 KB
  float2* stats = (float2*)(wsb + ((size_t)32 << 20) + (256 << 10)); // 8 KB

  gn_stats<<<dim3(BB * NG + 256), 256, 0, stream>>>(x, stats, qkvw, projw, wq16, wp16);
  gn_apply<<<dim3(BB * 16), 256, 0, stream>>>(x, stats, gw, gb, xt16);
  mgemm<0><<<dim3(16, 6, BB), 256, 0, stream>>>(wq16, xt16, Qb, nullptr, nullptr, nullptr);
  attn4<<<dim3(2048), 256, 0, stream>>>(Qb, Kb, Vb, xt16);
  mgemm<1><<<dim3(16, 2, BB), 256, 0, stream>>>(wp16, xt16, nullptr, out, projb, x);
}

// Round 11
// 70.775 us; speedup vs baseline: 1.2898x; 1.1820x over previous
//
#include <hip/hip_runtime.h>
#include <math.h>

#define BB 32
#define CC 128
#define HW 1024
#define NG 32
#define TPG 4096
#define QSZ ((size_t)BB * 4 * HW * 32)   // elems per Q/K/V bf16 buffer

typedef __attribute__((ext_vector_type(8))) short fragAB;
typedef __attribute__((ext_vector_type(4))) float fragC;

__device__ __forceinline__ ushort f2bf(float f) {
  union { float f; uint u; } v; v.f = f;
  uint r = v.u + 0x7FFFu + ((v.u >> 16) & 1u);
  return (ushort)(r >> 16);
}
// pack two f32 -> two bf16 (truncation) in one v_perm_b32
__device__ __forceinline__ uint pack2(float lo, float hi) {
  return __builtin_amdgcn_perm(__float_as_uint(hi), __float_as_uint(lo), 0x07060302u);
}
// LDS swizzle (byte offsets), 128B rows, g = 16B granule 0..7
__device__ __forceinline__ int vswz(int row, int g) {
  return row * 128 + 16 * (g ^ (row & 7));
}

// ---------------- GroupNorm stats (blocks 0..1023) + weight bf16 prep (1024..1279) ----
__global__ __launch_bounds__(256) void gn_stats(const float* __restrict__ x,
    float2* __restrict__ stats, const float* __restrict__ qkvw,
    const float* __restrict__ projw, ushort* __restrict__ wq16,
    ushort* __restrict__ wp16) {
  if (blockIdx.x >= 1024) {
    int idx = (blockIdx.x - 1024) * 256 + threadIdx.x;   // 0..65535
    if (idx < 49152) wq16[idx] = f2bf(qkvw[idx]);
    else             wp16[idx - 49152] = f2bf(projw[idx - 49152]);
    return;
  }
  int blk = blockIdx.x;          // b*NG + g
  int b = blk >> 5, g = blk & 31;
  const float4* xp4 = (const float4*)(x + ((size_t)(b * CC + g * 4)) * HW);
  float s = 0.f, s2 = 0.f;
  #pragma unroll
  for (int i = 0; i < 4; ++i) {
    float4 v = xp4[threadIdx.x + i * 256];
    s  += v.x + v.y + v.z + v.w;
    s2 += v.x * v.x + v.y * v.y + v.z * v.z + v.w * v.w;
  }
  #pragma unroll
  for (int off = 32; off; off >>= 1) {
    s  += __shfl_down(s, off, 64);
    s2 += __shfl_down(s2, off, 64);
  }
  __shared__ float ls[4], ls2[4];
  int lane = threadIdx.x & 63, wid = threadIdx.x >> 6;
  if (lane == 0) { ls[wid] = s; ls2[wid] = s2; }
  __syncthreads();
  if (threadIdx.x == 0) {
    float a  = ls[0] + ls[1] + ls[2] + ls[3];
    float a2 = ls2[0] + ls2[1] + ls2[2] + ls2[3];
    float mu = a * (1.f / TPG);
    float var = a2 * (1.f / TPG) - mu * mu;
    stats[blk] = make_float2(mu, rsqrtf(var + 1e-5f));
  }
}

// ---------------- GN apply + transpose: x[b][c][t] -> xt16[b][t][c] bf16 ----------------
__global__ __launch_bounds__(256) void gn_apply(const float* __restrict__ x,
    const float2* __restrict__ stats, const float* __restrict__ gw,
    const float* __restrict__ gb, ushort* __restrict__ xt16) {
  __shared__ ushort Xs[64][136];
  int b = blockIdx.x >> 4, t0 = (blockIdx.x & 15) * 64;
  int tid = threadIdx.x;
  int tq = tid & 15, cg = (tid >> 4) & 3, wv = tid >> 6;

  #pragma unroll
  for (int iter = 0; iter < 8; ++iter) {
    int c = wv * 4 + cg + iter * 16;
    float2 st = stats[b * 32 + (c >> 2)];
    float wsc = gw[c] * st.y;
    float bsc = gb[c] - st.x * wsc;
    const float* xp = x + ((size_t)b * CC + c) * HW + t0;
    #pragma unroll
    for (int j = 0; j < 4; ++j) {
      int t = tq + 16 * j;
      Xs[t][c] = f2bf(xp[t] * wsc + bsc);
    }
  }
  __syncthreads();
  #pragma unroll
  for (int it = 0; it < 4; ++it) {
    int row = (tid >> 4) + it * 16;
    int c8 = tid & 15;
    uint4 v = *(uint4*)&Xs[row][c8 * 8];
    *(uint4*)&xt16[((size_t)b * HW + t0 + row) * CC + c8 * 8] = v;
  }
}

// ---------------- MFMA GEMM: D[o,t] = sum_c W[o,c] * X[t,c] ----------------
// PROJ=0: scatter to FRAG-LINEAR Q/K/V buffers (q pre-scaled (1/32)*log2e).
//   Q/K frag layout: elem = bh*32768 + (s>>4)*512 + (c>>3)*128 + (s&15)*8 + (c&7)
//   V   frag layout: elem = bh*32768 + (s>>6)*2048 + (c>>4)*1024 + ((s&63)>>3)*128
//                         + (c&15)*8 + (s&7)
// PROJ=1: out fp32 [b][o][t] = D + bias[o] + resid[b][o][t].
template<int PROJ>
__global__ __launch_bounds__(256) void mgemm(
    const ushort* __restrict__ W16, const ushort* __restrict__ X16,
    ushort* __restrict__ Qb, float* __restrict__ out,
    const float* __restrict__ bias, const float* __restrict__ resid) {
  __shared__ ushort Xs[64 * 128];    // 16KB, XOR-swizzled byte ^= ((row&7)<<4)
  int b = blockIdx.z, o0 = blockIdx.y * 64, t0 = blockIdx.x * 64;
  int tid = threadIdx.x;
  int lane = tid & 63, w = tid >> 6, lc = lane & 15, lg = lane >> 4;
  int wo = w >> 1, wt = w & 1;

  fragAB af[2][4];
  #pragma unroll
  for (int i = 0; i < 2; ++i)
    #pragma unroll
    for (int kc = 0; kc < 4; ++kc)
      af[i][kc] = *(const fragAB*)&W16[(size_t)(o0 + wo * 32 + i * 16 + lc) * 128 + kc * 32 + lg * 8];

  {
    const char* src = (const char*)(X16 + ((size_t)b * HW + t0) * CC);
    char* dst = (char*)Xs;
    #pragma unroll
    for (int it = 0; it < 4; ++it) {
      int flat = tid * 16 + it * 4096;
      uint4 v = *(const uint4*)(src + flat);
      *(uint4*)(dst + (flat ^ (((flat >> 8) & 7) << 4))) = v;
    }
  }
  __syncthreads();

  fragC acc[2][2];
  #pragma unroll
  for (int i = 0; i < 2; ++i)
    #pragma unroll
    for (int j = 0; j < 2; ++j)
      acc[i][j] = (fragC){0.f, 0.f, 0.f, 0.f};

  #pragma unroll
  for (int kc = 0; kc < 4; ++kc) {
    fragAB bf[2];
    #pragma unroll
    for (int j = 0; j < 2; ++j) {
      int row = wt * 32 + j * 16 + lc;
      int byt = (row * 256 + kc * 64 + lg * 16) ^ ((row & 7) << 4);
      bf[j] = *(const fragAB*)((const char*)Xs + byt);
    }
    #pragma unroll
    for (int i = 0; i < 2; ++i)
      #pragma unroll
      for (int j = 0; j < 2; ++j)
        acc[i][j] = __builtin_amdgcn_mfma_f32_16x16x32_bf16(af[i][kc], bf[j], acc[i][j], 0, 0, 0);
  }

  if constexpr (PROJ == 0) {
    #pragma unroll
    for (int i = 0; i < 2; ++i) {
      int ob = o0 + wo * 32 + i * 16;
      int blk = ob >> 5;
      int hh = blk / 3, kind = blk % 3;  // 0=q,1=k,2=v
      size_t bh = (size_t)b * 4 + hh;
      float sc = (kind == 0) ? (0.03125f * 1.44269504f) : 1.f;
      #pragma unroll
      for (int j = 0; j < 2; ++j) {
        if (kind < 2) {
          // Q/K frag-linear ushort4 store
          ushort* dst = (kind == 0) ? Qb : (Qb + QSZ);
          int s16 = (t0 >> 4) + wt * 2 + j;
          int eo = s16 * 512 + (((ob & 16) >> 3) + (lg >> 1)) * 128 + lc * 8 + (lg & 1) * 4;
          ushort4 rv;
          rv.x = f2bf(acc[i][j][0] * sc); rv.y = f2bf(acc[i][j][1] * sc);
          rv.z = f2bf(acc[i][j][2] * sc); rv.w = f2bf(acc[i][j][3] * sc);
          *(ushort4*)&dst[bh * 32768 + eo] = rv;
        } else {
          // V frag-linear scalar stores (L2 merges sectors)
          ushort* Vb = Qb + 2 * QSZ;
          int eo = (t0 >> 6) * 2048 + ((ob & 16) >> 4) * 1024
                 + (wt * 4 + j * 2 + (lc >> 3)) * 128 + (lc & 7);
          #pragma unroll
          for (int r = 0; r < 4; ++r)
            Vb[bh * 32768 + eo + (lg * 4 + r) * 8] = f2bf(acc[i][j][r]);
        }
      }
    }
  } else {
    #pragma unroll
    for (int i = 0; i < 2; ++i)
      #pragma unroll
      for (int j = 0; j < 2; ++j) {
        int t = t0 + wt * 32 + j * 16 + lc;
        #pragma unroll
        for (int r = 0; r < 4; ++r) {
          int o = o0 + wo * 32 + i * 16 + lg * 4 + r;
          size_t idx = ((size_t)b * CC + o) * HW + t;
          out[idx] = acc[i][j][r] + bias[o] + resid[idx];
        }
      }
  }
}

// ---------------- MFMA flash attention v8: frag-linear global K/V, ZERO barriers ----
// Waves fully independent: 32 q/wave, kf/vf direct global (base + lane*16 + imm),
// static softmax exp2, wave-private Ps (LDS roundtrip only), wave-private Ol.
__global__ __launch_bounds__(256) void attn5(
    const ushort* __restrict__ Qb, const ushort* __restrict__ Kb,
    const ushort* __restrict__ Vb, ushort* __restrict__ ao16) {
  __shared__ char arena[4][2560];   // per wave: Ps [0,2048), Ol [0,2560) after Ps use

  int tid = threadIdx.x;
  int w = tid >> 6, lane = tid & 63, lc = lane & 15, lg = lane >> 4;
  int gw = (blockIdx.x & 7) * 512 + (blockIdx.x >> 3) * 4 + w;  // XCD swizzle
  int bh = gw >> 5, tb = gw & 31;
  int h = bh & 3, b = bh >> 2;

  const ushort* Qg = Qb + (size_t)bh * 32768 + (size_t)(tb * 2) * 512 + lane * 8;
  const ushort* Kg = Kb + (size_t)bh * 32768 + lane * 8;
  const ushort* Vg = Vb + (size_t)bh * 32768 + lane * 8;
  int t0 = tb * 32;

  fragAB q0 = *(const fragAB*)&Qg[0];
  fragAB q1 = *(const fragAB*)&Qg[512];

  fragC a00 = {0.f,0.f,0.f,0.f}, a01 = {0.f,0.f,0.f,0.f};
  fragC a10 = {0.f,0.f,0.f,0.f}, a11 = {0.f,0.f,0.f,0.f};
  float l0 = 0.f, l1 = 0.f;
  char* PsB = arena[w];

  for (int i = 0; i < 16; ++i) {
    const ushort* Kt = Kg + i * 2048;
    const ushort* Vt = Vg + i * 2048;
    fragAB kf[4], vf[4];
    #pragma unroll
    for (int j = 0; j < 4; ++j) kf[j] = *(const fragAB*)&Kt[j * 512];
    #pragma unroll
    for (int u = 0; u < 4; ++u) vf[u] = *(const fragAB*)&Vt[u * 512];  // u = cs*2+ks

    #pragma unroll
    for (int ts = 0; ts < 2; ++ts) {
      fragAB qf = ts ? q1 : q0;
      fragC S[4];
      #pragma unroll
      for (int j = 0; j < 4; ++j) {
        fragC z = {0.f,0.f,0.f,0.f};
        S[j] = __builtin_amdgcn_mfma_f32_16x16x32_bf16(kf[j], qf, z, 0, 0, 0);
      }
      float rs = 0.f;
      #pragma unroll
      for (int j = 0; j < 4; ++j) {
        float p0 = __builtin_amdgcn_exp2f(S[j][0]), p1 = __builtin_amdgcn_exp2f(S[j][1]);
        float p2 = __builtin_amdgcn_exp2f(S[j][2]), p3 = __builtin_amdgcn_exp2f(S[j][3]);
        rs += (p0 + p1) + (p2 + p3);
        uint2 wv2;
        wv2.x = pack2(p0, p1);
        wv2.y = pack2(p2, p3);
        int g = j * 2 + (lg >> 1);
        *(uint2*)(PsB + lc * 128 + 16 * (g ^ (lc & 7)) + (lg & 1) * 8) = wv2;
      }
      if (ts) l1 += rs; else l0 += rs;
      fragC* aA = ts ? &a01 : &a00;
      fragC* aB = ts ? &a11 : &a10;
      fragAB bp0 = *(const fragAB*)(PsB + vswz(lc, lg));
      fragAB bp1 = *(const fragAB*)(PsB + vswz(lc, 4 + lg));
      *aA = __builtin_amdgcn_mfma_f32_16x16x32_bf16(vf[0], bp0, *aA, 0, 0, 0);
      *aA = __builtin_amdgcn_mfma_f32_16x16x32_bf16(vf[1], bp1, *aA, 0, 0, 0);
      *aB = __builtin_amdgcn_mfma_f32_16x16x32_bf16(vf[2], bp0, *aB, 0, 0, 0);
      *aB = __builtin_amdgcn_mfma_f32_16x16x32_bf16(vf[3], bp1, *aB, 0, 0, 0);
    }
  }

  // single cross-lane l reduce (each lane summed a disjoint s-slice)
  l0 += __shfl_xor(l0, 16); l0 += __shfl_xor(l0, 32);
  l1 += __shfl_xor(l1, 16); l1 += __shfl_xor(l1, 32);
  float il0 = 1.f / l0, il1 = 1.f / l1;

  // wave-private Ol [32 t][40] -> coalesced global (same-wave LDS, no barrier)
  ushort* Ol = (ushort*)arena[w];
  uint2 u;
  u.x = pack2(a00[0] * il0, a00[1] * il0); u.y = pack2(a00[2] * il0, a00[3] * il0);
  *(uint2*)&Ol[lc * 40 + lg * 4] = u;
  u.x = pack2(a10[0] * il0, a10[1] * il0); u.y = pack2(a10[2] * il0, a10[3] * il0);
  *(uint2*)&Ol[lc * 40 + 16 + lg * 4] = u;
  u.x = pack2(a01[0] * il1, a01[1] * il1); u.y = pack2(a01[2] * il1, a01[3] * il1);
  *(uint2*)&Ol[(lc + 16) * 40 + lg * 4] = u;
  u.x = pack2(a11[0] * il1, a11[1] * il1); u.y = pack2(a11[2] * il1, a11[3] * il1);
  *(uint2*)&Ol[(lc + 16) * 40 + 16 + lg * 4] = u;

  int row = lane >> 1, half = lane & 1;
  uint4 v0 = *(uint4*)&Ol[row * 40 + half * 16];
  uint4 v1 = *(uint4*)&Ol[row * 40 + half * 16 + 8];
  ushort* dst = &ao16[((size_t)b * HW + t0 + row) * CC + h * 32 + half * 16];
  *(uint4*)dst = v0;
  *(uint4*)(dst + 8) = v1;
}

extern "C" void kernel_launch(void* const* d_in, const int* in_sizes, int n_in,
                              void* d_out, int out_size, void* d_ws, size_t ws_size,
                              hipStream_t stream) {
  (void)in_sizes; (void)n_in; (void)out_size; (void)ws_size;
  const float* x     = (const float*)d_in[0];
  const float* gw    = (const float*)d_in[1];
  const float* gb    = (const float*)d_in[2];
  const float* qkvw  = (const float*)d_in[3];
  const float* projw = (const float*)d_in[4];
  const float* projb = (const float*)d_in[5];
  float* out = (float*)d_out;

  char* wsb = (char*)d_ws;
  ushort* xt16 = (ushort*)wsb;                              // 8 MB (GN out, then attn out)
  ushort* Qb   = (ushort*)(wsb + ((size_t)8 << 20));        // 8 MB (frag-linear)
  ushort* Kb   = Qb + QSZ;                                  // 8 MB (frag-linear)
  ushort* Vb   = Qb + 2 * QSZ;                              // 8 MB (frag-linear)
  ushort* wq16 = (ushort*)(wsb + ((size_t)32 << 20));       // 96 KB
  ushort* wp16 = (ushort*)(wsb + ((size_t)32 << 20) + (128 << 10)); // 32 KB
  float2* stats = (float2*)(wsb + ((size_t)32 << 20) + (256 << 10)); // 8 KB

  gn_stats<<<dim3(BB * NG + 256), 256, 0, stream>>>(x, stats, qkvw, projw, wq16, wp16);
  gn_apply<<<dim3(BB * 16), 256, 0, stream>>>(x, stats, gw, gb, xt16);
  mgemm<0><<<dim3(16, 6, BB), 256, 0, stream>>>(wq16, xt16, Qb, nullptr, nullptr, nullptr);
  attn5<<<dim3(1024), 256, 0, stream>>>(Qb, Kb, Vb, xt16);
  mgemm<1><<<dim3(16, 2, BB), 256, 0, stream>>>(wp16, xt16, nullptr, out, projb, x);
}

// Round 12
// 69.641 us; speedup vs baseline: 1.3108x; 1.0163x over previous
//
#include <hip/hip_runtime.h>
#include <math.h>

#define BB 32
#define CC 128
#define HW 1024
#define NG 32
#define TPG 4096
#define QSZ ((size_t)BB * 4 * HW * 32)   // elems per Q/K/V bf16 buffer

typedef __attribute__((ext_vector_type(8))) short fragAB;
typedef __attribute__((ext_vector_type(4))) float fragC;
typedef __attribute__((ext_vector_type(8))) ushort ushort8v;

__device__ __forceinline__ ushort f2bf(float f) {
  union { float f; uint u; } v; v.f = f;
  uint r = v.u + 0x7FFFu + ((v.u >> 16) & 1u);
  return (ushort)(r >> 16);
}
// pack two f32 -> two bf16 (truncation) in one v_perm_b32
__device__ __forceinline__ uint pack2(float lo, float hi) {
  return __builtin_amdgcn_perm(__float_as_uint(hi), __float_as_uint(lo), 0x07060302u);
}
// LDS swizzle (byte offsets), 128B rows, g = 16B granule 0..7
__device__ __forceinline__ int vswz(int row, int g) {
  return row * 128 + 16 * (g ^ (row & 7));
}

// ---------------- GroupNorm stats (blocks 0..1023) + weight bf16 prep (1024..1279) ----
__global__ __launch_bounds__(256) void gn_stats(const float* __restrict__ x,
    float2* __restrict__ stats, const float* __restrict__ qkvw,
    const float* __restrict__ projw, ushort* __restrict__ wq16,
    ushort* __restrict__ wp16) {
  if (blockIdx.x >= 1024) {
    int idx = (blockIdx.x - 1024) * 256 + threadIdx.x;   // 0..65535
    if (idx < 49152) wq16[idx] = f2bf(qkvw[idx]);
    else             wp16[idx - 49152] = f2bf(projw[idx - 49152]);
    return;
  }
  int blk = blockIdx.x;          // b*NG + g
  int b = blk >> 5, g = blk & 31;
  const float4* xp4 = (const float4*)(x + ((size_t)(b * CC + g * 4)) * HW);
  float s = 0.f, s2 = 0.f;
  #pragma unroll
  for (int i = 0; i < 4; ++i) {
    float4 v = xp4[threadIdx.x + i * 256];
    s  += v.x + v.y + v.z + v.w;
    s2 += v.x * v.x + v.y * v.y + v.z * v.z + v.w * v.w;
  }
  #pragma unroll
  for (int off = 32; off; off >>= 1) {
    s  += __shfl_down(s, off, 64);
    s2 += __shfl_down(s2, off, 64);
  }
  __shared__ float ls[4], ls2[4];
  int lane = threadIdx.x & 63, wid = threadIdx.x >> 6;
  if (lane == 0) { ls[wid] = s; ls2[wid] = s2; }
  __syncthreads();
  if (threadIdx.x == 0) {
    float a  = ls[0] + ls[1] + ls[2] + ls[3];
    float a2 = ls2[0] + ls2[1] + ls2[2] + ls2[3];
    float mu = a * (1.f / TPG);
    float var = a2 * (1.f / TPG) - mu * mu;
    stats[blk] = make_float2(mu, rsqrtf(var + 1e-5f));
  }
}

// ---------------- MFMA GEMM: D[o,t] = sum_c W[o,c] * X[t,c] ----------------
// PROJ=0: X comes from fp32 x with GN fused into staging; output scattered to
//   FRAG-LINEAR Q/K/V (q pre-scaled (1/32)*log2e).
//   Q/K frag layout: elem = bh*32768 + (s>>4)*512 + (c>>3)*128 + (s&15)*8 + (c&7)
//   V   frag layout: elem = bh*32768 + (s>>6)*2048 + (c>>4)*1024 + ((s&63)>>3)*128
//                         + (c&15)*8 + (s&7)
// PROJ=1: X16 bf16 [b][t][c]; out fp32 = D + bias[o] + resid.
template<int PROJ>
__global__ __launch_bounds__(256) void mgemm(
    const ushort* __restrict__ W16, const ushort* __restrict__ X16,
    const float* __restrict__ xf, const float2* __restrict__ stats,
    const float* __restrict__ gw, const float* __restrict__ gb,
    ushort* __restrict__ Qb, float* __restrict__ out,
    const float* __restrict__ bias, const float* __restrict__ resid) {
  __shared__ ushort Xs[64 * 128];    // 16KB, XOR-swizzled byte ^= ((row&7)<<4)
  int b = blockIdx.z, o0 = blockIdx.y * 64, t0 = blockIdx.x * 64;
  int tid = threadIdx.x;
  int lane = tid & 63, w = tid >> 6, lc = lane & 15, lg = lane >> 4;
  int wo = w >> 1, wt = w & 1;

  fragAB af[2][4];
  #pragma unroll
  for (int i = 0; i < 2; ++i)
    #pragma unroll
    for (int kc = 0; kc < 4; ++kc)
      af[i][kc] = *(const fragAB*)&W16[(size_t)(o0 + wo * 32 + i * 16 + lc) * 128 + kc * 32 + lg * 8];

  if constexpr (PROJ == 0) {
    // fused-GN staging: x fp32 [c][t] -> Xs bf16 [t][c] swizzled
    int tq = tid & 15, co = tid >> 4;     // t-quad (4t), c-oct (8c)
    const float* xb = xf + (size_t)b * CC * HW + t0 + tq * 4;
    float wsc[8], bsc[8];
    {
      float2 s0 = stats[b * 32 + co * 2];
      float2 s1 = stats[b * 32 + co * 2 + 1];
      #pragma unroll
      for (int cc = 0; cc < 8; ++cc) {
        float rst = (cc < 4) ? s0.y : s1.y;
        float mu  = (cc < 4) ? s0.x : s1.x;
        float g = gw[co * 8 + cc];
        wsc[cc] = g * rst;
        bsc[cc] = gb[co * 8 + cc] - mu * wsc[cc];
      }
    }
    union { float4 v; float f[4]; } vv[8];
    #pragma unroll
    for (int cc = 0; cc < 8; ++cc)
      vv[cc].v = *(const float4*)&xb[(size_t)(co * 8 + cc) * HW];
    #pragma unroll
    for (int tt = 0; tt < 4; ++tt) {
      int row = tq * 4 + tt;
      ushort8v r;
      #pragma unroll
      for (int cc = 0; cc < 8; ++cc)
        r[cc] = f2bf(vv[cc].f[tt] * wsc[cc] + bsc[cc]);
      int byt = (row * 256 + co * 16) ^ ((row & 7) << 4);
      *(ushort8v*)((char*)Xs + byt) = r;
    }
  } else {
    const char* src = (const char*)(X16 + ((size_t)b * HW + t0) * CC);
    char* dst = (char*)Xs;
    #pragma unroll
    for (int it = 0; it < 4; ++it) {
      int flat = tid * 16 + it * 4096;
      uint4 v = *(const uint4*)(src + flat);
      *(uint4*)(dst + (flat ^ (((flat >> 8) & 7) << 4))) = v;
    }
  }
  __syncthreads();

  fragC acc[2][2];
  #pragma unroll
  for (int i = 0; i < 2; ++i)
    #pragma unroll
    for (int j = 0; j < 2; ++j)
      acc[i][j] = (fragC){0.f, 0.f, 0.f, 0.f};

  #pragma unroll
  for (int kc = 0; kc < 4; ++kc) {
    fragAB bf[2];
    #pragma unroll
    for (int j = 0; j < 2; ++j) {
      int row = wt * 32 + j * 16 + lc;
      int byt = (row * 256 + kc * 64 + lg * 16) ^ ((row & 7) << 4);
      bf[j] = *(const fragAB*)((const char*)Xs + byt);
    }
    #pragma unroll
    for (int i = 0; i < 2; ++i)
      #pragma unroll
      for (int j = 0; j < 2; ++j)
        acc[i][j] = __builtin_amdgcn_mfma_f32_16x16x32_bf16(af[i][kc], bf[j], acc[i][j], 0, 0, 0);
  }

  if constexpr (PROJ == 0) {
    #pragma unroll
    for (int i = 0; i < 2; ++i) {
      int ob = o0 + wo * 32 + i * 16;
      int blk = ob >> 5;
      int hh = blk / 3, kind = blk % 3;  // 0=q,1=k,2=v
      size_t bh = (size_t)b * 4 + hh;
      float sc = (kind == 0) ? (0.03125f * 1.44269504f) : 1.f;
      #pragma unroll
      for (int j = 0; j < 2; ++j) {
        if (kind < 2) {
          ushort* dst = (kind == 0) ? Qb : (Qb + QSZ);
          int s16 = (t0 >> 4) + wt * 2 + j;
          int eo = s16 * 512 + (((ob & 16) >> 3) + (lg >> 1)) * 128 + lc * 8 + (lg & 1) * 4;
          ushort4 rv;
          rv.x = f2bf(acc[i][j][0] * sc); rv.y = f2bf(acc[i][j][1] * sc);
          rv.z = f2bf(acc[i][j][2] * sc); rv.w = f2bf(acc[i][j][3] * sc);
          *(ushort4*)&dst[bh * 32768 + eo] = rv;
        } else {
          ushort* Vb = Qb + 2 * QSZ;
          int eo = (t0 >> 6) * 2048 + ((ob & 16) >> 4) * 1024
                 + (wt * 4 + j * 2 + (lc >> 3)) * 128 + (lc & 7);
          #pragma unroll
          for (int r = 0; r < 4; ++r)
            Vb[bh * 32768 + eo + (lg * 4 + r) * 8] = f2bf(acc[i][j][r]);
        }
      }
    }
  } else {
    #pragma unroll
    for (int i = 0; i < 2; ++i)
      #pragma unroll
      for (int j = 0; j < 2; ++j) {
        int t = t0 + wt * 32 + j * 16 + lc;
        #pragma unroll
        for (int r = 0; r < 4; ++r) {
          int o = o0 + wo * 32 + i * 16 + lg * 4 + r;
          size_t idx = ((size_t)b * CC + o) * HW + t;
          out[idx] = acc[i][j][r] + bias[o] + resid[idx];
        }
      }
  }
}

// ---------------- MFMA flash attention v9: frag-linear K/V + s-split wave pairs ----
// Wave pair (w, w^1) shares one 32-query tile; wave handles s-half (w&1).
// Static softmax: unnormalized acc and per-lane l are additive across s.
// One barrier total (combine).
__global__ __launch_bounds__(256) void attn6(
    const ushort* __restrict__ Qb, const ushort* __restrict__ Kb,
    const ushort* __restrict__ Vb, ushort* __restrict__ ao16) {
  __shared__ char arena[17408];
  // [0,8192): Ps per wave 2048B. [8192,17408): combine 2 pairs x 64 lanes x 72B.
  // Ol (post-barrier): pair p at arena + p*4096, 2560B.

  int tid = threadIdx.x;
  int w = tid >> 6, lane = tid & 63, lc = lane & 15, lg = lane >> 4;
  int lb = blockIdx.x;
  int gp = (lb & 7) * 256 + (lb >> 3);   // XCD swizzle: 16 bh per XCD
  int bh = gp >> 4, qp = gp & 15;
  int h = bh & 3, b = bh >> 2;
  int qt = qp * 2 + (w >> 1);            // q-tile 0..31
  int sh = w & 1;                        // s-half
  int t0 = qt * 32;

  const ushort* Qg = Qb + (size_t)bh * 32768 + (size_t)qt * 1024 + lane * 8;
  const ushort* Kg = Kb + (size_t)bh * 32768 + lane * 8;
  const ushort* Vg = Vb + (size_t)bh * 32768 + lane * 8;

  fragAB q0 = *(const fragAB*)&Qg[0];
  fragAB q1 = *(const fragAB*)&Qg[512];

  fragC a00 = {0.f,0.f,0.f,0.f}, a01 = {0.f,0.f,0.f,0.f};
  fragC a10 = {0.f,0.f,0.f,0.f}, a11 = {0.f,0.f,0.f,0.f};
  float l0 = 0.f, l1 = 0.f;
  char* PsB = arena + w * 2048;

  for (int i = sh * 8; i < sh * 8 + 8; ++i) {
    const ushort* Kt = Kg + i * 2048;
    const ushort* Vt = Vg + i * 2048;
    fragAB kf[4], vf[4];
    #pragma unroll
    for (int j = 0; j < 4; ++j) kf[j] = *(const fragAB*)&Kt[j * 512];
    #pragma unroll
    for (int u = 0; u < 4; ++u) vf[u] = *(const fragAB*)&Vt[u * 512];  // u = cs*2+ks

    #pragma unroll
    for (int ts = 0; ts < 2; ++ts) {
      fragAB qf = ts ? q1 : q0;
      fragC S[4];
      #pragma unroll
      for (int j = 0; j < 4; ++j) {
        fragC z = {0.f,0.f,0.f,0.f};
        S[j] = __builtin_amdgcn_mfma_f32_16x16x32_bf16(kf[j], qf, z, 0, 0, 0);
      }
      float rs = 0.f;
      #pragma unroll
      for (int j = 0; j < 4; ++j) {
        float p0 = __builtin_amdgcn_exp2f(S[j][0]), p1 = __builtin_amdgcn_exp2f(S[j][1]);
        float p2 = __builtin_amdgcn_exp2f(S[j][2]), p3 = __builtin_amdgcn_exp2f(S[j][3]);
        rs += (p0 + p1) + (p2 + p3);
        uint2 wv2;
        wv2.x = pack2(p0, p1);
        wv2.y = pack2(p2, p3);
        int g = j * 2 + (lg >> 1);
        *(uint2*)(PsB + lc * 128 + 16 * (g ^ (lc & 7)) + (lg & 1) * 8) = wv2;
      }
      if (ts) l1 += rs; else l0 += rs;
      fragC* aA = ts ? &a01 : &a00;
      fragC* aB = ts ? &a11 : &a10;
      fragAB bp0 = *(const fragAB*)(PsB + vswz(lc, lg));
      fragAB bp1 = *(const fragAB*)(PsB + vswz(lc, 4 + lg));
      *aA = __builtin_amdgcn_mfma_f32_16x16x32_bf16(vf[0], bp0, *aA, 0, 0, 0);
      *aA = __builtin_amdgcn_mfma_f32_16x16x32_bf16(vf[1], bp1, *aA, 0, 0, 0);
      *aB = __builtin_amdgcn_mfma_f32_16x16x32_bf16(vf[2], bp0, *aB, 0, 0, 0);
      *aB = __builtin_amdgcn_mfma_f32_16x16x32_bf16(vf[3], bp1, *aB, 0, 0, 0);
    }
  }

  // combine the two s-halves of each pair
  float* comb = (float*)(arena + 8192);
  float* slot = comb + ((w >> 1) * 64 + lane) * 18;
  if (sh == 1) {
    #pragma unroll
    for (int r = 0; r < 4; ++r) {
      slot[r]      = a00[r];
      slot[4 + r]  = a10[r];
      slot[8 + r]  = a01[r];
      slot[12 + r] = a11[r];
    }
    slot[16] = l0;
    slot[17] = l1;
  }
  __syncthreads();
  if (sh == 1) return;

  #pragma unroll
  for (int r = 0; r < 4; ++r) {
    a00[r] += slot[r];
    a10[r] += slot[4 + r];
    a01[r] += slot[8 + r];
    a11[r] += slot[12 + r];
  }
  l0 += slot[16];
  l1 += slot[17];

  l0 += __shfl_xor(l0, 16); l0 += __shfl_xor(l0, 32);
  l1 += __shfl_xor(l1, 16); l1 += __shfl_xor(l1, 32);
  float il0 = 1.f / l0, il1 = 1.f / l1;

  // Ol [32 t][40] (wave-private, same-wave LDS -> no barrier) -> coalesced global
  ushort* Ol = (ushort*)(arena + (w >> 1) * 4096);
  uint2 u;
  u.x = pack2(a00[0] * il0, a00[1] * il0); u.y = pack2(a00[2] * il0, a00[3] * il0);
  *(uint2*)&Ol[lc * 40 + lg * 4] = u;
  u.x = pack2(a10[0] * il0, a10[1] * il0); u.y = pack2(a10[2] * il0, a10[3] * il0);
  *(uint2*)&Ol[lc * 40 + 16 + lg * 4] = u;
  u.x = pack2(a01[0] * il1, a01[1] * il1); u.y = pack2(a01[2] * il1, a01[3] * il1);
  *(uint2*)&Ol[(lc + 16) * 40 + lg * 4] = u;
  u.x = pack2(a11[0] * il1, a11[1] * il1); u.y = pack2(a11[2] * il1, a11[3] * il1);
  *(uint2*)&Ol[(lc + 16) * 40 + 16 + lg * 4] = u;

  int row = lane >> 1, half = lane & 1;
  uint4 v0 = *(uint4*)&Ol[row * 40 + half * 16];
  uint4 v1 = *(uint4*)&Ol[row * 40 + half * 16 + 8];
  ushort* dst = &ao16[((size_t)b * HW + t0 + row) * CC + h * 32 + half * 16];
  *(uint4*)dst = v0;
  *(uint4*)(dst + 8) = v1;
}

extern "C" void kernel_launch(void* const* d_in, const int* in_sizes, int n_in,
                              void* d_out, int out_size, void* d_ws, size_t ws_size,
                              hipStream_t stream) {
  (void)in_sizes; (void)n_in; (void)out_size; (void)ws_size;
  const float* x     = (const float*)d_in[0];
  const float* gw    = (const float*)d_in[1];
  const float* gb    = (const float*)d_in[2];
  const float* qkvw  = (const float*)d_in[3];
  const float* projw = (const float*)d_in[4];
  const float* projb = (const float*)d_in[5];
  float* out = (float*)d_out;

  char* wsb = (char*)d_ws;
  ushort* ao16 = (ushort*)wsb;                              // 8 MB (attn out)
  ushort* Qb   = (ushort*)(wsb + ((size_t)8 << 20));        // 8 MB (frag-linear)
  ushort* Kb   = Qb + QSZ;                                  // 8 MB (frag-linear)
  ushort* Vb   = Qb + 2 * QSZ;                              // 8 MB (frag-linear)
  ushort* wq16 = (ushort*)(wsb + ((size_t)32 << 20));       // 96 KB
  ushort* wp16 = (ushort*)(wsb + ((size_t)32 << 20) + (128 << 10)); // 32 KB
  float2* stats = (float2*)(wsb + ((size_t)32 << 20) + (256 << 10)); // 8 KB

  gn_stats<<<dim3(BB * NG + 256), 256, 0, stream>>>(x, stats, qkvw, projw, wq16, wp16);
  mgemm<0><<<dim3(16, 6, BB), 256, 0, stream>>>(wq16, nullptr, x, stats, gw, gb,
                                                Qb, nullptr, nullptr, nullptr);
  attn6<<<dim3(2048), 256, 0, stream>>>(Qb, Kb, Vb, ao16);
  mgemm<1><<<dim3(16, 2, BB), 256, 0, stream>>>(wp16, ao16, nullptr, nullptr, nullptr, nullptr,
                                                nullptr, out, projb, x);
}